// Round 4
// baseline (254.403 us; speedup 1.0000x reference)
//
#include <hip/hip_runtime.h>
#include <math.h>

#define NROWS 16384   // B*T
#define DDIM  2048
#define NEXP  16
#define RBLOCKS 512   // router grid: 32 rows/block
#define WPB 8         // waves per 512-thread block
#define ZN (RBLOCKS * WPB)

__device__ __forceinline__ float fnoise(float x) {
    return copysignf(sqrtf(fabsf(x)), x);
}

// ws layout (float idx):
//   [0, 32768)       w_noisy [E][D]
//   [32768, 32784)   b_noisy [E]
//   [32800, 36896)   zpartial [ZN] (one float per wave)

// Vectorized prep: 8192 threads x float4. Same per-element expression as the
// verified scalar version -> bitwise-compatible.
__global__ void prep_kernel(const float* __restrict__ weight,
                            const float* __restrict__ sigma_weight,
                            const float* __restrict__ bias,
                            const float* __restrict__ sigma_bias,
                            const float* __restrict__ eps_in,
                            const float* __restrict__ eps_out,
                            float* __restrict__ w_noisy,
                            float* __restrict__ b_noisy) {
    int gid = blockIdx.x * blockDim.x + threadIdx.x;   // 0 .. 8191 (float4 idx)
    int e  = gid >> 9;          // 512 float4 per expert row
    int c4 = gid & 511;         // float4 column
    float4 w  = ((const float4*)weight)[gid];
    float4 sw = ((const float4*)sigma_weight)[gid];
    float4 ei = ((const float4*)eps_in)[c4];
    float fo = fnoise(eps_out[e]);
    float4 r;
    r.x = w.x + sw.x * fo * fnoise(ei.x);
    r.y = w.y + sw.y * fo * fnoise(ei.y);
    r.z = w.z + sw.z * fo * fnoise(ei.z);
    r.w = w.w + sw.w * fo * fnoise(ei.w);
    ((float4*)w_noisy)[gid] = r;
    if (gid < 4) {   // experts 4*gid .. 4*gid+3
        float4 b  = ((const float4*)bias)[gid];
        float4 sb = ((const float4*)sigma_bias)[gid];
        float4 eo = ((const float4*)eps_out)[gid];
        float4 rb;
        rb.x = b.x + sb.x * fnoise(eo.x);
        rb.y = b.y + sb.y * fnoise(eo.y);
        rb.z = b.z + sb.z * fnoise(eo.z);
        rb.w = b.w + sb.w * fnoise(eo.w);
        ((float4*)b_noisy)[gid] = rb;
    }
}

// Barrier-free router. w_noisy is 128 KiB and read by every block -> it is
// permanently L2-hot (and L1-hot across the 16 co-resident waves streaming
// the same 16 KiB/chunk). So: NO LDS staging, NO DMA, NO __syncthreads.
// Each wave free-runs over its 4 rows; per chunk the compiler hoists the
// 16 w float4-loads + 4 x float4-loads -> ~20 outstanding VMEM per wave,
// latency hidden by MLP instead of bulk-sync double buffering.
// Inner FMA block / butterfly / epilogue identical to the verified R0 code.
__global__ __launch_bounds__(512, 4) void router_kernel(
        const float* __restrict__ x,        // [NROWS][DDIM]
        const float* __restrict__ w_noisy,  // [E][D]
        const float* __restrict__ b_noisy,  // [E]
        float* __restrict__ out_router,     // [NROWS][E]
        float* __restrict__ out_idx,        // [NROWS][2] stored as float
        float* __restrict__ zpart) {        // [ZN]
    const int tid  = threadIdx.x;
    const int wv   = tid >> 6;
    const int lane = tid & 63;

    const int rowBase = blockIdx.x * 32 + wv * 4;
    const float4* xr0 = (const float4*)(x + (size_t)(rowBase + 0) * DDIM);
    const float4* xr1 = (const float4*)(x + (size_t)(rowBase + 1) * DDIM);
    const float4* xr2 = (const float4*)(x + (size_t)(rowBase + 2) * DDIM);
    const float4* xr3 = (const float4*)(x + (size_t)(rowBase + 3) * DDIM);
    const float4* wsrc = (const float4*)w_noisy;  // [16][512] float4

    float acc[64];
    #pragma unroll
    for (int i = 0; i < 64; ++i) acc[i] = 0.0f;

    float4 xbuf[2][4];
    xbuf[0][0] = xr0[lane];
    xbuf[0][1] = xr1[lane];
    xbuf[0][2] = xr2[lane];
    xbuf[0][3] = xr3[lane];

    #pragma unroll
    for (int c = 0; c < 8; ++c) {           // 8 chunks of 64 float4 cols
        const int xc = c & 1;
        const int xn = xc ^ 1;
        if (c < 7) {
            // x prefetch for chunk c+1 (consumed next chunk)
            int p = (c + 1) * 64 + lane;
            xbuf[xn][0] = xr0[p];
            xbuf[xn][1] = xr1[p];
            xbuf[xn][2] = xr2[p];
            xbuf[xn][3] = xr3[p];
        }
        #pragma unroll
        for (int e = 0; e < 16; ++e) {
            // same element as the staged version: w_noisy[e][c*256 + lane*4 ..]
            float4 w = wsrc[e * 512 + c * 64 + lane];
            float s0 = acc[0 * 16 + e];
            float s1 = acc[1 * 16 + e];
            float s2 = acc[2 * 16 + e];
            float s3 = acc[3 * 16 + e];
            s0 = fmaf(xbuf[xc][0].x, w.x, s0); s0 = fmaf(xbuf[xc][0].y, w.y, s0);
            s0 = fmaf(xbuf[xc][0].z, w.z, s0); s0 = fmaf(xbuf[xc][0].w, w.w, s0);
            s1 = fmaf(xbuf[xc][1].x, w.x, s1); s1 = fmaf(xbuf[xc][1].y, w.y, s1);
            s1 = fmaf(xbuf[xc][1].z, w.z, s1); s1 = fmaf(xbuf[xc][1].w, w.w, s1);
            s2 = fmaf(xbuf[xc][2].x, w.x, s2); s2 = fmaf(xbuf[xc][2].y, w.y, s2);
            s2 = fmaf(xbuf[xc][2].z, w.z, s2); s2 = fmaf(xbuf[xc][2].w, w.w, s2);
            s3 = fmaf(xbuf[xc][3].x, w.x, s3); s3 = fmaf(xbuf[xc][3].y, w.y, s3);
            s3 = fmaf(xbuf[xc][3].z, w.z, s3); s3 = fmaf(xbuf[xc][3].w, w.w, s3);
            acc[0 * 16 + e] = s0;
            acc[1 * 16 + e] = s1;
            acc[2 * 16 + e] = s2;
            acc[3 * 16 + e] = s3;
        }
    }

    // Butterfly transpose-reduce: lane l ends with full sum of index l
    // (l = r*16 + e over this wave's 4 rows x 16 experts).
    #pragma unroll
    for (int half = 32; half >= 1; half >>= 1) {
        #pragma unroll
        for (int i = 0; i < half; ++i) {
            bool hi = (lane & half) != 0;
            float keep = hi ? acc[i + half] : acc[i];
            float send = hi ? acc[i] : acc[i + half];
            float recv = __shfl_xor(send, half, 64);
            acc[i] = keep + recv;
        }
    }

    const int e = lane & 15;           // expert owned by this lane
    const int r = lane >> 4;           // local row 0..3
    const int row = rowBase + r;
    float logit = acc[0] + b_noisy[e];

    // top-1 with lower-index tie-break within the 16-lane group
    float m1 = logit; int i1 = e;
    #pragma unroll
    for (int off = 8; off >= 1; off >>= 1) {
        float om = __shfl_xor(m1, off, 64);
        int   oi = __shfl_xor(i1, off, 64);
        if (om > m1 || (om == m1 && oi < i1)) { m1 = om; i1 = oi; }
    }
    // top-2: mask out i1
    float v2 = (e == i1) ? -3.4e38f : logit;
    float m2 = v2; int i2 = e;
    #pragma unroll
    for (int off = 8; off >= 1; off >>= 1) {
        float om = __shfl_xor(m2, off, 64);
        int   oi = __shfl_xor(i2, off, 64);
        if (om > m2 || (om == m2 && oi < i2)) { m2 = om; i2 = oi; }
    }

    // softmax over sparse logits: exp(-1e30 - m1) == 0 exactly, so only
    // positions i1, i2 are nonzero.
    float t = expf(m2 - m1);
    float p1 = 1.0f / (1.0f + t);
    float val = (e == i1) ? p1 : ((e == i2) ? t * p1 : 0.0f);
    out_router[(size_t)rowBase * NEXP + lane] = val;   // fully coalesced

    if (e < 2) {
        out_idx[(size_t)row * 2 + e] = (float)((e == 0) ? i1 : i2);
    }

    // z-loss partial: sum lse^2 over this wave's 4 rows, no atomics.
    float zv = 0.0f;
    if (e == 0) {
        float lse = m1 + log1pf(t);
        zv = lse * lse;
    }
    zv += __shfl_xor(zv, 16, 64);
    zv += __shfl_xor(zv, 32, 64);
    if (lane == 0) {
        zpart[blockIdx.x * WPB + wv] = zv;
    }
}

__global__ void finalize_kernel(const float* __restrict__ zpart,
                                float* __restrict__ out) {
    __shared__ float ws4[4];
    int tid = threadIdx.x;   // 256 threads
    float s = 0.0f;
    for (int i = tid; i < ZN; i += 256) s += zpart[i];
    #pragma unroll
    for (int off = 32; off >= 1; off >>= 1) s += __shfl_xor(s, off, 64);
    if ((tid & 63) == 0) ws4[tid >> 6] = s;
    __syncthreads();
    if (tid == 0) {
        float total = ws4[0] + ws4[1] + ws4[2] + ws4[3];
        out[NROWS * NEXP + NROWS * 2] = total * (1.0f / (float)NROWS);
    }
}

extern "C" void kernel_launch(void* const* d_in, const int* in_sizes, int n_in,
                              void* d_out, int out_size, void* d_ws, size_t ws_size,
                              hipStream_t stream) {
    const float* mh      = (const float*)d_in[0];
    const float* weight  = (const float*)d_in[1];
    const float* sigw    = (const float*)d_in[2];
    const float* bias    = (const float*)d_in[3];
    const float* sigb    = (const float*)d_in[4];
    const float* eps_in  = (const float*)d_in[5];
    const float* eps_out = (const float*)d_in[6];

    float* out      = (float*)d_out;
    float* w_noisy  = (float*)d_ws;
    float* b_noisy  = w_noisy + NEXP * DDIM;     // float idx 32768
    float* zpart    = w_noisy + 32800;           // float idx 32800, 128B-aligned

    prep_kernel<<<32, 256, 0, stream>>>(
        weight, sigw, bias, sigb, eps_in, eps_out, w_noisy, b_noisy);

    router_kernel<<<RBLOCKS, 512, 0, stream>>>(
        mh, w_noisy, b_noisy, out, out + NROWS * NEXP, zpart);

    finalize_kernel<<<1, 256, 0, stream>>>(zpart, out);
}

// Round 5
// 227.606 us; speedup vs baseline: 1.1177x; 1.1177x over previous
//
#include <hip/hip_runtime.h>
#include <math.h>

#define NROWS 16384   // B*T
#define DDIM  2048
#define NEXP  16
#define RBLOCKS 512   // router grid: 32 rows/block
#define WPB 8         // waves per 512-thread block
#define ZN (RBLOCKS * WPB)

__device__ __forceinline__ float fnoise(float x) {
    return copysignf(sqrtf(fabsf(x)), x);
}

// ws layout (float idx):
//   [0, 32768)       w_noisy [E][D]
//   [32768, 32784)   b_noisy [E]
//   [32800, 36896)   zpartial [ZN] (one float per wave)

// Vectorized prep: 8192 threads x float4. Same per-element expression as the
// verified scalar version -> bitwise-compatible.
__global__ void prep_kernel(const float* __restrict__ weight,
                            const float* __restrict__ sigma_weight,
                            const float* __restrict__ bias,
                            const float* __restrict__ sigma_bias,
                            const float* __restrict__ eps_in,
                            const float* __restrict__ eps_out,
                            float* __restrict__ w_noisy,
                            float* __restrict__ b_noisy) {
    int gid = blockIdx.x * blockDim.x + threadIdx.x;   // 0 .. 8191 (float4 idx)
    int e  = gid >> 9;          // 512 float4 per expert row
    int c4 = gid & 511;         // float4 column
    float4 w  = ((const float4*)weight)[gid];
    float4 sw = ((const float4*)sigma_weight)[gid];
    float4 ei = ((const float4*)eps_in)[c4];
    float fo = fnoise(eps_out[e]);
    float4 r;
    r.x = w.x + sw.x * fo * fnoise(ei.x);
    r.y = w.y + sw.y * fo * fnoise(ei.y);
    r.z = w.z + sw.z * fo * fnoise(ei.z);
    r.w = w.w + sw.w * fo * fnoise(ei.w);
    ((float4*)w_noisy)[gid] = r;
    if (gid < 4) {   // experts 4*gid .. 4*gid+3
        float4 b  = ((const float4*)bias)[gid];
        float4 sb = ((const float4*)sigma_bias)[gid];
        float4 eo = ((const float4*)eps_out)[gid];
        float4 rb;
        rb.x = b.x + sb.x * fnoise(eo.x);
        rb.y = b.y + sb.y * fnoise(eo.y);
        rb.z = b.z + sb.z * fnoise(eo.z);
        rb.w = b.w + sb.w * fnoise(eo.w);
        ((float4*)b_noisy)[gid] = rb;
    }
}

// Barrier-free router, spill-fixed. R4 evidence: with __launch_bounds__(512,4)
// the allocator was capped ~128 VGPRs and spilled acc[64] to scratch
// (WRITE_SIZE 92 MB). Live set here is ~170-200 regs (acc 64 + xbuf 32 +
// ~16 w-float4 in flight + addresses), so declare min-waves=1 to lift the
// cap. Occupancy drops to ~2-3 waves/SIMD, but each wave free-runs with
// ~20 VMEM outstanding and 512 issue-cycles of FMA per chunk covering the
// L2-hit w latency. w_noisy (128 KiB, read by all blocks) stays L2-hot.
// Inner FMA block / butterfly / epilogue identical to the verified R0 code.
__global__ __launch_bounds__(512, 1) void router_kernel(
        const float* __restrict__ x,        // [NROWS][DDIM]
        const float* __restrict__ w_noisy,  // [E][D]
        const float* __restrict__ b_noisy,  // [E]
        float* __restrict__ out_router,     // [NROWS][E]
        float* __restrict__ out_idx,        // [NROWS][2] stored as float
        float* __restrict__ zpart) {        // [ZN]
    const int tid  = threadIdx.x;
    const int wv   = tid >> 6;
    const int lane = tid & 63;

    const int rowBase = blockIdx.x * 32 + wv * 4;
    const float4* xr0 = (const float4*)(x + (size_t)(rowBase + 0) * DDIM);
    const float4* xr1 = (const float4*)(x + (size_t)(rowBase + 1) * DDIM);
    const float4* xr2 = (const float4*)(x + (size_t)(rowBase + 2) * DDIM);
    const float4* xr3 = (const float4*)(x + (size_t)(rowBase + 3) * DDIM);
    const float4* wsrc = (const float4*)w_noisy;  // [16][512] float4

    float acc[64];
    #pragma unroll
    for (int i = 0; i < 64; ++i) acc[i] = 0.0f;

    float4 xbuf[2][4];
    xbuf[0][0] = xr0[lane];
    xbuf[0][1] = xr1[lane];
    xbuf[0][2] = xr2[lane];
    xbuf[0][3] = xr3[lane];

    #pragma unroll
    for (int c = 0; c < 8; ++c) {           // 8 chunks of 64 float4 cols
        const int xc = c & 1;
        const int xn = xc ^ 1;
        if (c < 7) {
            // x prefetch for chunk c+1 (consumed next chunk)
            int p = (c + 1) * 64 + lane;
            xbuf[xn][0] = xr0[p];
            xbuf[xn][1] = xr1[p];
            xbuf[xn][2] = xr2[p];
            xbuf[xn][3] = xr3[p];
        }
        #pragma unroll
        for (int e = 0; e < 16; ++e) {
            // same element as the staged version: w_noisy[e][c*256 + lane*4 ..]
            float4 w = wsrc[e * 512 + c * 64 + lane];
            float s0 = acc[0 * 16 + e];
            float s1 = acc[1 * 16 + e];
            float s2 = acc[2 * 16 + e];
            float s3 = acc[3 * 16 + e];
            s0 = fmaf(xbuf[xc][0].x, w.x, s0); s0 = fmaf(xbuf[xc][0].y, w.y, s0);
            s0 = fmaf(xbuf[xc][0].z, w.z, s0); s0 = fmaf(xbuf[xc][0].w, w.w, s0);
            s1 = fmaf(xbuf[xc][1].x, w.x, s1); s1 = fmaf(xbuf[xc][1].y, w.y, s1);
            s1 = fmaf(xbuf[xc][1].z, w.z, s1); s1 = fmaf(xbuf[xc][1].w, w.w, s1);
            s2 = fmaf(xbuf[xc][2].x, w.x, s2); s2 = fmaf(xbuf[xc][2].y, w.y, s2);
            s2 = fmaf(xbuf[xc][2].z, w.z, s2); s2 = fmaf(xbuf[xc][2].w, w.w, s2);
            s3 = fmaf(xbuf[xc][3].x, w.x, s3); s3 = fmaf(xbuf[xc][3].y, w.y, s3);
            s3 = fmaf(xbuf[xc][3].z, w.z, s3); s3 = fmaf(xbuf[xc][3].w, w.w, s3);
            acc[0 * 16 + e] = s0;
            acc[1 * 16 + e] = s1;
            acc[2 * 16 + e] = s2;
            acc[3 * 16 + e] = s3;
        }
    }

    // Butterfly transpose-reduce: lane l ends with full sum of index l
    // (l = r*16 + e over this wave's 4 rows x 16 experts).
    #pragma unroll
    for (int half = 32; half >= 1; half >>= 1) {
        #pragma unroll
        for (int i = 0; i < half; ++i) {
            bool hi = (lane & half) != 0;
            float keep = hi ? acc[i + half] : acc[i];
            float send = hi ? acc[i] : acc[i + half];
            float recv = __shfl_xor(send, half, 64);
            acc[i] = keep + recv;
        }
    }

    const int e = lane & 15;           // expert owned by this lane
    const int r = lane >> 4;           // local row 0..3
    const int row = rowBase + r;
    float logit = acc[0] + b_noisy[e];

    // top-1 with lower-index tie-break within the 16-lane group
    float m1 = logit; int i1 = e;
    #pragma unroll
    for (int off = 8; off >= 1; off >>= 1) {
        float om = __shfl_xor(m1, off, 64);
        int   oi = __shfl_xor(i1, off, 64);
        if (om > m1 || (om == m1 && oi < i1)) { m1 = om; i1 = oi; }
    }
    // top-2: mask out i1
    float v2 = (e == i1) ? -3.4e38f : logit;
    float m2 = v2; int i2 = e;
    #pragma unroll
    for (int off = 8; off >= 1; off >>= 1) {
        float om = __shfl_xor(m2, off, 64);
        int   oi = __shfl_xor(i2, off, 64);
        if (om > m2 || (om == m2 && oi < i2)) { m2 = om; i2 = oi; }
    }

    // softmax over sparse logits: exp(-1e30 - m1) == 0 exactly, so only
    // positions i1, i2 are nonzero.
    float t = expf(m2 - m1);
    float p1 = 1.0f / (1.0f + t);
    float val = (e == i1) ? p1 : ((e == i2) ? t * p1 : 0.0f);
    out_router[(size_t)rowBase * NEXP + lane] = val;   // fully coalesced

    if (e < 2) {
        out_idx[(size_t)row * 2 + e] = (float)((e == 0) ? i1 : i2);
    }

    // z-loss partial: sum lse^2 over this wave's 4 rows, no atomics.
    float zv = 0.0f;
    if (e == 0) {
        float lse = m1 + log1pf(t);
        zv = lse * lse;
    }
    zv += __shfl_xor(zv, 16, 64);
    zv += __shfl_xor(zv, 32, 64);
    if (lane == 0) {
        zpart[blockIdx.x * WPB + wv] = zv;
    }
}

__global__ void finalize_kernel(const float* __restrict__ zpart,
                                float* __restrict__ out) {
    __shared__ float ws4[4];
    int tid = threadIdx.x;   // 256 threads
    float s = 0.0f;
    for (int i = tid; i < ZN; i += 256) s += zpart[i];
    #pragma unroll
    for (int off = 32; off >= 1; off >>= 1) s += __shfl_xor(s, off, 64);
    if ((tid & 63) == 0) ws4[tid >> 6] = s;
    __syncthreads();
    if (tid == 0) {
        float total = ws4[0] + ws4[1] + ws4[2] + ws4[3];
        out[NROWS * NEXP + NROWS * 2] = total * (1.0f / (float)NROWS);
    }
}

extern "C" void kernel_launch(void* const* d_in, const int* in_sizes, int n_in,
                              void* d_out, int out_size, void* d_ws, size_t ws_size,
                              hipStream_t stream) {
    const float* mh      = (const float*)d_in[0];
    const float* weight  = (const float*)d_in[1];
    const float* sigw    = (const float*)d_in[2];
    const float* bias    = (const float*)d_in[3];
    const float* sigb    = (const float*)d_in[4];
    const float* eps_in  = (const float*)d_in[5];
    const float* eps_out = (const float*)d_in[6];

    float* out      = (float*)d_out;
    float* w_noisy  = (float*)d_ws;
    float* b_noisy  = w_noisy + NEXP * DDIM;     // float idx 32768
    float* zpart    = w_noisy + 32800;           // float idx 32800, 128B-aligned

    prep_kernel<<<32, 256, 0, stream>>>(
        weight, sigw, bias, sigb, eps_in, eps_out, w_noisy, b_noisy);

    router_kernel<<<RBLOCKS, 512, 0, stream>>>(
        mh, w_noisy, b_noisy, out, out + NROWS * NEXP, zpart);

    finalize_kernel<<<1, 256, 0, stream>>>(zpart, out);
}

// Round 6
// 211.154 us; speedup vs baseline: 1.2048x; 1.0779x over previous
//
#include <hip/hip_runtime.h>
#include <math.h>

#define NROWS 16384   // B*T
#define DDIM  2048
#define NEXP  16
#define RBLOCKS 1024  // router grid: 16 rows/block, 4 blocks/CU co-resident
#define WPB 4         // waves per 256-thread block
#define ZN (RBLOCKS * WPB)

__device__ __forceinline__ float fnoise(float x) {
    return copysignf(sqrtf(fabsf(x)), x);
}

// async 16B global -> LDS (no VGPR round-trip). Pass the wave-uniform LDS
// base; HW adds lane*16. Source pointer includes +lane.
__device__ __forceinline__ void async_copy16(const float4* g, float4* l) {
    __builtin_amdgcn_global_load_lds(
        (const __attribute__((address_space(1))) void*)g,
        (__attribute__((address_space(3))) void*)l, 16, 0, 0);
}

// ws layout (float idx):
//   [0, 32768)       w_noisy [E][D]
//   [32768, 32784)   b_noisy [E]
//   [32800, 36896)   zpartial [ZN] (one float per wave)

// Vectorized prep: 8192 threads x float4. Same per-element expression as the
// verified scalar version -> bitwise-compatible.
__global__ void prep_kernel(const float* __restrict__ weight,
                            const float* __restrict__ sigma_weight,
                            const float* __restrict__ bias,
                            const float* __restrict__ sigma_bias,
                            const float* __restrict__ eps_in,
                            const float* __restrict__ eps_out,
                            float* __restrict__ w_noisy,
                            float* __restrict__ b_noisy) {
    int gid = blockIdx.x * blockDim.x + threadIdx.x;   // 0 .. 8191 (float4 idx)
    int e  = gid >> 9;          // 512 float4 per expert row
    int c4 = gid & 511;         // float4 column
    float4 w  = ((const float4*)weight)[gid];
    float4 sw = ((const float4*)sigma_weight)[gid];
    float4 ei = ((const float4*)eps_in)[c4];
    float fo = fnoise(eps_out[e]);
    float4 r;
    r.x = w.x + sw.x * fo * fnoise(ei.x);
    r.y = w.y + sw.y * fo * fnoise(ei.y);
    r.z = w.z + sw.z * fo * fnoise(ei.z);
    r.w = w.w + sw.w * fo * fnoise(ei.w);
    ((float4*)w_noisy)[gid] = r;
    if (gid < 4) {   // experts 4*gid .. 4*gid+3
        float4 b  = ((const float4*)bias)[gid];
        float4 sb = ((const float4*)sigma_bias)[gid];
        float4 eo = ((const float4*)eps_out)[gid];
        float4 rb;
        rb.x = b.x + sb.x * fnoise(eo.x);
        rb.y = b.y + sb.y * fnoise(eo.y);
        rb.z = b.z + sb.z * fnoise(eo.z);
        rb.w = b.w + sb.w * fnoise(eo.w);
        ((float4*)b_noisy)[gid] = rb;
    }
}

// Occupancy-first staged router. R5 evidence: all variants pin VALUBusy ~17%
// with every other pipe idle -> latency-bound, too few resident waves
// (64.5 KiB LDS capped us at 2 blocks/CU). This version: 256-thread blocks
// (4 waves, 16 rows), w staged per CHUNK (2 x 16 KiB = 32 KiB LDS) -> 4
// blocks/CU co-resident (grid 1024 = 4 x 256 CUs exactly). launch_bounds
// (256,4) keeps the same 128-unified-reg cap R1 proved this inner loop fits
// (VGPR_Count 64 + acc in AGPRs, no spill). Inner FMA block / butterfly /
// epilogue byte-identical to the verified R0 code. Barriers are plain
// __syncthreads (vmcnt(0) drain) - one per chunk; the drain stalls overlap
// across the 4 independent blocks per CU.
__global__ __launch_bounds__(256, 4) void router_kernel(
        const float* __restrict__ x,        // [NROWS][DDIM]
        const float* __restrict__ w_noisy,  // [E][D]
        const float* __restrict__ b_noisy,  // [E]
        float* __restrict__ out_router,     // [NROWS][E]
        float* __restrict__ out_idx,        // [NROWS][2] stored as float
        float* __restrict__ zpart) {        // [ZN]
    __shared__ float4 wlds[2][NEXP * 64];   // 2 x 16 KiB chunks, [16][64] float4

    const int tid  = threadIdx.x;
    const int wv   = tid >> 6;              // 0..3
    const int lane = tid & 63;

    const int rowBase = blockIdx.x * 16 + wv * 4;
    const float4* xr0 = (const float4*)(x + (size_t)(rowBase + 0) * DDIM);
    const float4* xr1 = (const float4*)(x + (size_t)(rowBase + 1) * DDIM);
    const float4* xr2 = (const float4*)(x + (size_t)(rowBase + 2) * DDIM);
    const float4* xr3 = (const float4*)(x + (size_t)(rowBase + 3) * DDIM);
    const float4* wsrc = (const float4*)w_noisy;  // [16][512] float4

    float acc[64];
    #pragma unroll
    for (int i = 0; i < 64; ++i) acc[i] = 0.0f;

    float4 xbuf[2][4];

    // ---- prologue: stage chunk 0 -> wlds[0] (16x64 float4, 4/thread);
    // flat float4 idx fb = j*256 + wv*64 (wave-uniform, 64-aligned), expert
    // e = fb>>6 constant across the wave's lanes; src = wsrc[e*512 + c*64 + lane].
    #pragma unroll
    for (int j = 0; j < 4; ++j) {
        int fb = j * 256 + wv * 64;
        async_copy16(wsrc + (size_t)(fb >> 6) * 512 + lane, &wlds[0][fb]);
    }
    xbuf[0][0] = xr0[lane];
    xbuf[0][1] = xr1[lane];
    xbuf[0][2] = xr2[lane];
    xbuf[0][3] = xr3[lane];
    __syncthreads();   // chunk 0 in LDS (vmcnt(0) drain), x0 landed

    #pragma unroll
    for (int c = 0; c < 8; ++c) {           // 8 chunks of 64 float4 cols
        const int cb = c & 1;
        const int nb = cb ^ 1;
        const int xc = c & 1;
        const int xn = xc ^ 1;
        if (c < 7) {
            // stage chunk c+1 into the other buffer; drained by the
            // end-of-chunk __syncthreads
            #pragma unroll
            for (int j = 0; j < 4; ++j) {
                int fb = j * 256 + wv * 64;
                async_copy16(wsrc + (size_t)(fb >> 6) * 512 + (c + 1) * 64 + lane,
                             &wlds[nb][fb]);
            }
            // x prefetch for chunk c+1 (consumed next chunk)
            int p = (c + 1) * 64 + lane;
            xbuf[xn][0] = xr0[p];
            xbuf[xn][1] = xr1[p];
            xbuf[xn][2] = xr2[p];
            xbuf[xn][3] = xr3[p];
        }
        #pragma unroll
        for (int e = 0; e < 16; ++e) {
            float4 w = wlds[cb][e * 64 + lane];
            float s0 = acc[0 * 16 + e];
            float s1 = acc[1 * 16 + e];
            float s2 = acc[2 * 16 + e];
            float s3 = acc[3 * 16 + e];
            s0 = fmaf(xbuf[xc][0].x, w.x, s0); s0 = fmaf(xbuf[xc][0].y, w.y, s0);
            s0 = fmaf(xbuf[xc][0].z, w.z, s0); s0 = fmaf(xbuf[xc][0].w, w.w, s0);
            s1 = fmaf(xbuf[xc][1].x, w.x, s1); s1 = fmaf(xbuf[xc][1].y, w.y, s1);
            s1 = fmaf(xbuf[xc][1].z, w.z, s1); s1 = fmaf(xbuf[xc][1].w, w.w, s1);
            s2 = fmaf(xbuf[xc][2].x, w.x, s2); s2 = fmaf(xbuf[xc][2].y, w.y, s2);
            s2 = fmaf(xbuf[xc][2].z, w.z, s2); s2 = fmaf(xbuf[xc][2].w, w.w, s2);
            s3 = fmaf(xbuf[xc][3].x, w.x, s3); s3 = fmaf(xbuf[xc][3].y, w.y, s3);
            s3 = fmaf(xbuf[xc][3].z, w.z, s3); s3 = fmaf(xbuf[xc][3].w, w.w, s3);
            acc[0 * 16 + e] = s0;
            acc[1 * 16 + e] = s1;
            acc[2 * 16 + e] = s2;
            acc[3 * 16 + e] = s3;
        }
        if (c < 7) __syncthreads();   // chunk c+1 landed; all waves done with c
    }

    // Butterfly transpose-reduce: lane l ends with full sum of index l
    // (l = r*16 + e over this wave's 4 rows x 16 experts).
    #pragma unroll
    for (int half = 32; half >= 1; half >>= 1) {
        #pragma unroll
        for (int i = 0; i < half; ++i) {
            bool hi = (lane & half) != 0;
            float keep = hi ? acc[i + half] : acc[i];
            float send = hi ? acc[i] : acc[i + half];
            float recv = __shfl_xor(send, half, 64);
            acc[i] = keep + recv;
        }
    }

    const int e = lane & 15;           // expert owned by this lane
    const int r = lane >> 4;           // local row 0..3
    const int row = rowBase + r;
    float logit = acc[0] + b_noisy[e];

    // top-1 with lower-index tie-break within the 16-lane group
    float m1 = logit; int i1 = e;
    #pragma unroll
    for (int off = 8; off >= 1; off >>= 1) {
        float om = __shfl_xor(m1, off, 64);
        int   oi = __shfl_xor(i1, off, 64);
        if (om > m1 || (om == m1 && oi < i1)) { m1 = om; i1 = oi; }
    }
    // top-2: mask out i1
    float v2 = (e == i1) ? -3.4e38f : logit;
    float m2 = v2; int i2 = e;
    #pragma unroll
    for (int off = 8; off >= 1; off >>= 1) {
        float om = __shfl_xor(m2, off, 64);
        int   oi = __shfl_xor(i2, off, 64);
        if (om > m2 || (om == m2 && oi < i2)) { m2 = om; i2 = oi; }
    }

    // softmax over sparse logits: exp(-1e30 - m1) == 0 exactly, so only
    // positions i1, i2 are nonzero.
    float t = expf(m2 - m1);
    float p1 = 1.0f / (1.0f + t);
    float val = (e == i1) ? p1 : ((e == i2) ? t * p1 : 0.0f);
    out_router[(size_t)rowBase * NEXP + lane] = val;   // fully coalesced

    if (e < 2) {
        out_idx[(size_t)row * 2 + e] = (float)((e == 0) ? i1 : i2);
    }

    // z-loss partial: sum lse^2 over this wave's 4 rows, no atomics.
    float zv = 0.0f;
    if (e == 0) {
        float lse = m1 + log1pf(t);
        zv = lse * lse;
    }
    zv += __shfl_xor(zv, 16, 64);
    zv += __shfl_xor(zv, 32, 64);
    if (lane == 0) {
        zpart[blockIdx.x * WPB + wv] = zv;
    }
}

__global__ void finalize_kernel(const float* __restrict__ zpart,
                                float* __restrict__ out) {
    __shared__ float ws4[4];
    int tid = threadIdx.x;   // 256 threads
    float s = 0.0f;
    for (int i = tid; i < ZN; i += 256) s += zpart[i];
    #pragma unroll
    for (int off = 32; off >= 1; off >>= 1) s += __shfl_xor(s, off, 64);
    if ((tid & 63) == 0) ws4[tid >> 6] = s;
    __syncthreads();
    if (tid == 0) {
        float total = ws4[0] + ws4[1] + ws4[2] + ws4[3];
        out[NROWS * NEXP + NROWS * 2] = total * (1.0f / (float)NROWS);
    }
}

extern "C" void kernel_launch(void* const* d_in, const int* in_sizes, int n_in,
                              void* d_out, int out_size, void* d_ws, size_t ws_size,
                              hipStream_t stream) {
    const float* mh      = (const float*)d_in[0];
    const float* weight  = (const float*)d_in[1];
    const float* sigw    = (const float*)d_in[2];
    const float* bias    = (const float*)d_in[3];
    const float* sigb    = (const float*)d_in[4];
    const float* eps_in  = (const float*)d_in[5];
    const float* eps_out = (const float*)d_in[6];

    float* out      = (float*)d_out;
    float* w_noisy  = (float*)d_ws;
    float* b_noisy  = w_noisy + NEXP * DDIM;     // float idx 32768
    float* zpart    = w_noisy + 32800;           // float idx 32800, 128B-aligned

    prep_kernel<<<32, 256, 0, stream>>>(
        weight, sigw, bias, sigb, eps_in, eps_out, w_noisy, b_noisy);

    router_kernel<<<RBLOCKS, 256, 0, stream>>>(
        mh, w_noisy, b_noisy, out, out + NROWS * NEXP, zpart);

    finalize_kernel<<<1, 256, 0, stream>>>(zpart, out);
}